// Round 18
// baseline (83.983 us; speedup 1.0000x reference)
//
#include <hip/hip_runtime.h>
#include <hip/hip_bf16.h>
#include <stdint.h>

#define T_TOK 2048
#define DHID  1024
#define NEXP  16
#define MR    256
#define MS    512
#define CAP   512

typedef float  f32x4  __attribute__((ext_vector_type(4)));
typedef __bf16 bf16x8 __attribute__((ext_vector_type(8)));

typedef __attribute__((address_space(3))) void       lds_void;
typedef const __attribute__((address_space(1))) void gbl_void;

#define GLOAD16(g, l) __builtin_amdgcn_global_load_lds((gbl_void*)(g), (lds_void*)(l), 16, 0, 0)
#define VMCNT4() asm volatile("s_waitcnt vmcnt(4)" ::: "memory")
#define VMCNT0() asm volatile("s_waitcnt vmcnt(0)" ::: "memory")
#define SCHED_FENCE() __builtin_amdgcn_sched_barrier(0)

// LDS (ushort units, 32 KB total): A slots 0,4096 ; B slots 8192,12288
#define AOFF(t) (((t) & 1) * 4096)
#define BOFF(t) (8192 + ((t) & 1) * 4096)

__device__ __forceinline__ void barrier_raw() {
  asm volatile("" ::: "memory");
  __builtin_amdgcn_s_barrier();
  asm volatile("" ::: "memory");
}

__device__ __forceinline__ ushort f2bf(float f) {
  uint32_t u = __float_as_uint(f);
  u = (u + 0x7fffu + ((u >> 16) & 1u)) >> 16;
  return (ushort)u;
}
__device__ __forceinline__ float bf2f(ushort v) { return __uint_as_float(((uint32_t)v) << 16); }

// ---- T2 staging, BK=32: 128x32 bf16 tile (8 KB = 4096 ushorts), linear LDS dest ----
// shot s (s=0,1) covers rows [s*64, s*64+64) -> ushort offsets [s*2048, s*2048+2048)
// LDS[row][colE] holds global[row][colE ^ ((row&3)<<3)]
__device__ __forceinline__ void stage32(const ushort* __restrict__ g0, int strideE,
                                        ushort* lds, int tid) {
  const int wave = tid >> 6;
  const int r = tid >> 2, colE = (tid & 3) * 8;
#pragma unroll
  for (int s = 0; s < 2; ++s) {
    const int row = s * 64 + r;
    GLOAD16(g0 + (size_t)row * strideE + (colE ^ ((row & 3) << 3)), lds + s * 2048 + wave * 512);
  }
}

__device__ __forceinline__ void stage_gather32(const ushort* __restrict__ xb,
                                               const int tok[2], int k0,
                                               ushort* lds, int tid) {
  const int wave = tid >> 6;
  const int r = tid >> 2, colE = (tid & 3) * 8;
#pragma unroll
  for (int s = 0; s < 2; ++s) {
    const int row = s * 64 + r;
    GLOAD16(xb + (size_t)tok[s] * DHID + k0 + (colE ^ ((row & 3) << 3)), lds + s * 2048 + wave * 512);
  }
}

// ---- one BK=32 step of the 128x128 tile: 16 MFMA/wave, XOR-swizzled ds_read ----
__device__ __forceinline__ void mfma_tile32(const ushort* a_sh, const ushort* b_sh,
                                            int wr, int wc, int lane, f32x4 (&acc)[4][4]) {
  const int rb = lane & 15;
  const int k8 = (((lane >> 4) << 3)) ^ ((rb & 3) << 3);
  __builtin_amdgcn_s_setprio(1);
  bf16x8 af[4];
#pragma unroll
  for (int m = 0; m < 4; m++)
    af[m] = *(const bf16x8*)&a_sh[(wr * 64 + m * 16 + rb) * 32 + k8];
#pragma unroll
  for (int n = 0; n < 4; n++) {
    bf16x8 bf = *(const bf16x8*)&b_sh[(wc * 64 + n * 16 + rb) * 32 + k8];
#pragma unroll
    for (int m = 0; m < 4; m++)
      acc[m][n] = __builtin_amdgcn_mfma_f32_16x16x32_bf16(af[m], bf, acc[m][n], 0, 0, 0);
  }
  __builtin_amdgcn_s_setprio(0);
}

// ---- routed M-tile lookup from cnt[]: mti -> (e, s0, c) ----
__device__ __forceinline__ bool queue_lookup(const int* __restrict__ cnt, int mti,
                                             int& e_out, int& s0_out, int& c_out) {
  int acc = 0;
#pragma unroll
  for (int ee = 0; ee < NEXP; ++ee) {
    const int c = cnt[ee];
    const int ntl = (c + 127) >> 7;
    if (mti < acc + ntl) { e_out = ee; s0_out = (mti - acc) << 7; c_out = c; return true; }
    acc += ntl;
  }
  return false;
}

// ---------------- transpose tile worker ----------------
struct TP {
  const float* in; ushort* out;
  int R, C, out_ld, ilv;
  long long out_batch;
};

__device__ __forceinline__ void tpose_tile(const TP p, int local, void* smem, int tid) {
  float (*t_sh)[65] = (float(*)[65])smem;
  const int tr = p.R >> 6, tc = p.C >> 6, per = tr * tc;
  const int b = local / per, rem = local - b * per;
  const int rt = rem / tc, ct = rem - rt * tc;
  const int r0 = rt * 64, c0 = ct * 64;
  const float* ip = p.in + (size_t)b * p.R * p.C;
  ushort* op = p.out + (size_t)b * p.out_batch;
  const int trd = tid >> 4, tcd = (tid & 15) * 4;
#pragma unroll
  for (int q = 0; q < 4; q++) {
    float4 v = *(const float4*)&ip[(size_t)(r0 + trd + q * 16) * p.C + c0 + tcd];
    t_sh[trd + q * 16][tcd + 0] = v.x; t_sh[trd + q * 16][tcd + 1] = v.y;
    t_sh[trd + q * 16][tcd + 2] = v.z; t_sh[trd + q * 16][tcd + 3] = v.w;
  }
  __syncthreads();
#pragma unroll
  for (int q = 0; q < 4; q++) {
    const int cc = trd + q * 16;
    int rr = c0 + cc;
    if (p.ilv) rr = ((rr >> 4) << 5) + (rr & 15);   // 16-row g/u interleave slot
    ushort4 o;
    o.x = f2bf(t_sh[tcd + 0][cc]); o.y = f2bf(t_sh[tcd + 1][cc]);
    o.z = f2bf(t_sh[tcd + 2][cc]); o.w = f2bf(t_sh[tcd + 3][cc]);
    *(ushort4*)&op[(size_t)rr * p.out_ld + r0 + tcd] = o;
  }
}

// ---------------- k_prep: x->bf16 + fp32 router (standalone) ----------------
__global__ __launch_bounds__(256) void k_prep(
    const float* __restrict__ x, const float* __restrict__ rw,
    ushort* __restrict__ xb, int* __restrict__ topi, float2* __restrict__ topw)
{
  __shared__ float rw_sh[NEXP][DHID];   // 64 KB, transposed [e][d]
  const int tid = threadIdx.x;
#pragma unroll
  for (int it = 0; it < 16; ++it) {
    const int flat = it * 1024 + tid * 4;
    float4 v = *(const float4*)&rw[flat];
    const int d = flat >> 4, e = flat & 15;
    rw_sh[e + 0][d] = v.x; rw_sh[e + 1][d] = v.y;
    rw_sh[e + 2][d] = v.z; rw_sh[e + 3][d] = v.w;
  }
  __syncthreads();

  const int wave = tid >> 6, lane = tid & 63;
  for (int tk = 0; tk < 2; ++tk) {
    const int t = blockIdx.x * 8 + wave * 2 + tk;
    const float* xp = x + (size_t)t * DHID;
    float acc[NEXP];
#pragma unroll
    for (int e = 0; e < NEXP; e++) acc[e] = 0.f;
#pragma unroll
    for (int i = 0; i < 4; ++i) {
      const int d4 = i * 64 + lane;
      float4 xv = *(const float4*)&xp[d4 * 4];
      ushort4 o; o.x = f2bf(xv.x); o.y = f2bf(xv.y); o.z = f2bf(xv.z); o.w = f2bf(xv.w);
      *(ushort4*)&xb[(size_t)t * DHID + d4 * 4] = o;
#pragma unroll
      for (int e = 0; e < NEXP; e++) {
        float4 wv = *(const float4*)&rw_sh[e][d4 * 4];
        acc[e] = fmaf(xv.x, wv.x, acc[e]);
        acc[e] = fmaf(xv.y, wv.y, acc[e]);
        acc[e] = fmaf(xv.z, wv.z, acc[e]);
        acc[e] = fmaf(xv.w, wv.w, acc[e]);
      }
    }
#pragma unroll
    for (int off = 32; off >= 1; off >>= 1) {
#pragma unroll
      for (int e = 0; e < NEXP; e++) acc[e] += __shfl_xor(acc[e], off, 64);
    }
    if (lane == 0) {
      float m = acc[0];
#pragma unroll
      for (int e = 1; e < NEXP; e++) m = fmaxf(m, acc[e]);
      float p[NEXP], Z = 0.f;
#pragma unroll
      for (int e = 0; e < NEXP; e++) { p[e] = __expf(acc[e] - m); Z += p[e]; }
      const float inv = 1.f / Z;
      int i1 = 0; float p1 = p[0] * inv;
      for (int e = 1; e < NEXP; e++) { float pe = p[e] * inv; if (pe > p1) { p1 = pe; i1 = e; } }
      int i2 = -1; float p2 = -1.f;
      for (int e = 0; e < NEXP; e++) { if (e == i1) continue; float pe = p[e] * inv; if (pe > p2) { p2 = pe; i2 = e; } }
      const float denom = p1 + p2 + 1e-9f;
      topi[t] = i1 | (i2 << 8);
      topw[t] = make_float2(p1 / denom, p2 / denom);
    }
  }
}

// ---------------- k_build (blocks 0..15) + wgu transposes (2560 blocks) ----------------
__global__ __launch_bounds__(256) void k_build_tp(
    const int* __restrict__ topi, const float2* __restrict__ topw,
    int* __restrict__ cnt, int* __restrict__ ltok, float* __restrict__ lw,
    int* __restrict__ tslot, TP t0, TP t1, TP t2, TP t3)
{
  __shared__ float t_smem[64][65];     // 16.6 KB
  const int tid = threadIdx.x;
  const int bid = blockIdx.x;
  if (bid >= NEXP) {
    const int local = bid - NEXP;
    if      (local < 1024) tpose_tile(t0, local,        t_smem, tid);
    else if (local < 2048) tpose_tile(t1, local - 1024, t_smem, tid);
    else if (local < 2304) tpose_tile(t2, local - 2048, t_smem, tid);
    else                   tpose_tile(t3, local - 2304, t_smem, tid);
    return;
  }
  int* wsum = (int*)t_smem;
  const int e = bid;
  const int wave = tid >> 6, lane = tid & 63;
  const int t0i = tid * 8;

  int4 a = *(const int4*)&topi[t0i];
  int4 b = *(const int4*)&topi[t0i + 4];
  int ti[8] = {a.x, a.y, a.z, a.w, b.x, b.y, b.z, b.w};
  int match[8]; int c = 0;
#pragma unroll
  for (int k = 0; k < 8; ++k) {
    const int i1 = ti[k] & 0xff, i2 = (ti[k] >> 8) & 0xff;
    match[k] = (i1 == e) ? 1 : ((i2 == e) ? 2 : 0);
    c += (match[k] != 0);
  }
  int incl = c;
#pragma unroll
  for (int off = 1; off < 64; off <<= 1) {
    int n = __shfl_up(incl, off, 64);
    if (lane >= off) incl += n;
  }
  if (lane == 63) wsum[wave] = incl;
  __syncthreads();
  int base = incl - c;
  for (int w = 0; w < wave; ++w) base += wsum[w];
  if (tid == 0) {
    int tot = wsum[0] + wsum[1] + wsum[2] + wsum[3];
    cnt[e] = tot > CAP ? CAP : tot;
  }
#pragma unroll
  for (int k = 0; k < 8; ++k) {
    if (match[k]) {
      const int t = t0i + k;
      if (base < CAP) {
        float2 w2 = topw[t];
        ltok[e * CAP + base] = t;
        lw[e * CAP + base] = (match[k] == 1) ? w2.x : w2.y;
        tslot[t * 2 + (match[k] - 1)] = e * CAP + base;
      } else {
        tslot[t * 2 + (match[k] - 1)] = -1;
      }
      base++;
    }
  }
}

// ---------------- k_up: up GEMMs (512, BK=32 counted-vmcnt dbuf, 32 KB LDS) + wd tposes ----------------
__global__ __launch_bounds__(256) void k_up(
    const ushort* __restrict__ xb, const ushort* __restrict__ wguTs,
    const ushort* __restrict__ wguTr, const int* __restrict__ cnt,
    const int* __restrict__ ltok, const float* __restrict__ lw,
    ushort* __restrict__ h_s, ushort* __restrict__ h_r, TP t4, TP t5)
{
  __shared__ ushort smem[4 * 128 * 32];        // 32 KB: A0 | A1 | B0 | B1
  ushort (*r_sh)[64] = (ushort(*)[64])smem;    // 16 KB epilogue alias
  const int tid = threadIdx.x, lane = tid & 63, wave = tid >> 6;
  const int wr = wave >> 1, wc = wave & 1;
  const int rb = lane & 15, rowoff = (lane >> 4) << 2;
  const int bid0 = blockIdx.x;
  if (bid0 >= 512) {
    const int local = bid0 - 512;
    if (local < 1024) tpose_tile(t4, local, smem, tid);
    else              tpose_tile(t5, local - 1024, smem, tid);
    return;
  }
  f32x4 acc[4][4] = {};

  if (bid0 < 256) {
    const int bid = (bid0 & 7) * 32 + (bid0 >> 3);   // bijective swizzle within [0,256)
    const int mt = bid & 15, nt = bid >> 4;
    const ushort* Ab = xb + (size_t)mt * 128 * DHID;
    const ushort* Bb = wguTs + (size_t)nt * 128 * DHID;
    stage32(Ab, DHID, smem + AOFF(0), tid);
    stage32(Bb, DHID, smem + BOFF(0), tid);
    for (int t = 0; t < 32; ++t) {
      if (t < 31) {
        stage32(Ab + (t + 1) * 32, DHID, smem + AOFF(t + 1), tid);
        stage32(Bb + (t + 1) * 32, DHID, smem + BOFF(t + 1), tid);
        SCHED_FENCE();
        VMCNT4();
      } else {
        SCHED_FENCE();
        VMCNT0();
      }
      SCHED_FENCE();
      barrier_raw();
      SCHED_FENCE();
      mfma_tile32(smem + AOFF(t), smem + BOFF(t), wr, wc, lane, acc);
      SCHED_FENCE();
      barrier_raw();
    }
#pragma unroll
    for (int m = 0; m < 4; m++)
#pragma unroll
      for (int p = 0; p < 2; p++) {
        f32x4 g = acc[m][2 * p], u = acc[m][2 * p + 1];
#pragma unroll
        for (int jj = 0; jj < 4; jj++) {
          float gv = g[jj];
          float hv = (gv / (1.f + __expf(-gv))) * u[jj];
          r_sh[wr * 64 + m * 16 + rowoff + jj][wc * 32 + p * 16 + rb] = f2bf(hv);
        }
      }
    __syncthreads();
#pragma unroll
    for (int sp = 0; sp < 4; sp++) {
      const int row = sp * 32 + (tid >> 3), col = (tid & 7) * 8;
      *(uint4*)&h_s[(size_t)(mt * 128 + row) * DHID + nt * 64 + col] = *(const uint4*)&r_sh[row][col];
    }
  } else {
    const int id = bid0 - 256;                 // round-robin spreads dead blocks
    const int mti = id >> 2, ntile = id & 3;
    int e, s0, c;
    if (!queue_lookup(cnt, mti, e, s0, c)) return;
    int tok[2];
#pragma unroll
    for (int s = 0; s < 2; ++s) {
      int slot = s0 + s * 64 + (tid >> 2);
      if (slot >= c) slot = c - 1;
      tok[s] = ltok[e * CAP + slot];
    }
    const ushort* Bb = wguTr + ((size_t)e * 512 + ntile * 128) * DHID;
    stage_gather32(xb, tok, 0, smem + AOFF(0), tid);
    stage32(Bb, DHID, smem + BOFF(0), tid);
    for (int t = 0; t < 32; ++t) {
      if (t < 31) {
        stage_gather32(xb, tok, (t + 1) * 32, smem + AOFF(t + 1), tid);
        stage32(Bb + (t + 1) * 32, DHID, smem + BOFF(t + 1), tid);
        SCHED_FENCE();
        VMCNT4();
      } else {
        SCHED_FENCE();
        VMCNT0();
      }
      SCHED_FENCE();
      barrier_raw();
      SCHED_FENCE();
      mfma_tile32(smem + AOFF(t), smem + BOFF(t), wr, wc, lane, acc);
      SCHED_FENCE();
      barrier_raw();
    }
#pragma unroll
    for (int m = 0; m < 4; m++)
#pragma unroll
      for (int jj = 0; jj < 4; jj++) {
        const int slot = s0 + wr * 64 + m * 16 + rowoff + jj;
        const float w = (slot < c) ? lw[e * CAP + slot] : 0.f;
#pragma unroll
        for (int p = 0; p < 2; p++) {
          float gv = acc[m][2 * p][jj];
          float hv = (gv / (1.f + __expf(-gv))) * acc[m][2 * p + 1][jj] * w;
          r_sh[wr * 64 + m * 16 + rowoff + jj][wc * 32 + p * 16 + rb] = f2bf(hv);
        }
      }
    __syncthreads();
#pragma unroll
    for (int sp = 0; sp < 4; sp++) {
      const int row = sp * 32 + (tid >> 3), col = (tid & 7) * 8;
      *(uint4*)&h_r[((size_t)e * CAP + s0 + row) * MR + ntile * 64 + col] = *(const uint4*)&r_sh[row][col];
    }
  }
}

// ---------------- k_down: merged down GEMMs (BK=32 counted-vmcnt dbuf, 32 KB LDS) ----------------
__global__ __launch_bounds__(256) void k_down(
    const ushort* __restrict__ h_s, const ushort* __restrict__ wdTs,
    const ushort* __restrict__ h_r, const ushort* __restrict__ wdTr,
    const int* __restrict__ cnt, ushort* __restrict__ ds, ushort* __restrict__ dr)
{
  __shared__ ushort smem[4 * 128 * 32];          // 32 KB
  ushort (*r2)[128] = (ushort(*)[128])smem;      // full 32 KB epilogue alias
  const int tid = threadIdx.x, lane = tid & 63, wave = tid >> 6;
  const int wr = wave >> 1, wc = wave & 1;
  const int rb = lane & 15, rowoff = (lane >> 4) << 2;
  f32x4 acc[4][4] = {};
  const int bid0 = blockIdx.x;

  const ushort* Ab; const ushort* Bb;
  int K, rowbase, colbase; ushort* outp;
  if (bid0 < 128) {
    const int bid = (bid0 & 7) * 16 + (bid0 >> 3);   // bijective swizzle within [0,128)
    const int mt = bid >> 3, nt = bid & 7;
    Ab = h_s + (size_t)mt * 128 * DHID;
    Bb = wdTs + (size_t)nt * 128 * DHID;
    K = DHID; rowbase = mt * 128; colbase = nt * 128;
    outp = ds;
  } else {
    const int id = bid0 - 128;
    const int mti = id >> 3, nt = id & 7;
    int e, s0, c;
    if (!queue_lookup(cnt, mti, e, s0, c)) return;
    Ab = h_r + ((size_t)e * CAP + s0) * MR;
    Bb = wdTr + ((size_t)e * DHID + nt * 128) * MR;
    K = MR; rowbase = e * CAP + s0; colbase = nt * 128;
    outp = dr;
  }
  const int nk = K >> 5;
  stage32(Ab, K, smem + AOFF(0), tid);
  stage32(Bb, K, smem + BOFF(0), tid);
  for (int t = 0; t < nk; ++t) {
    if (t + 1 < nk) {
      stage32(Ab + (t + 1) * 32, K, smem + AOFF(t + 1), tid);
      stage32(Bb + (t + 1) * 32, K, smem + BOFF(t + 1), tid);
      SCHED_FENCE();
      VMCNT4();
    } else {
      SCHED_FENCE();
      VMCNT0();
    }
    SCHED_FENCE();
    barrier_raw();
    SCHED_FENCE();
    mfma_tile32(smem + AOFF(t), smem + BOFF(t), wr, wc, lane, acc);
    SCHED_FENCE();
    barrier_raw();
  }
#pragma unroll
  for (int m = 0; m < 4; m++)
#pragma unroll
    for (int n = 0; n < 4; n++) {
      f32x4 v = acc[m][n];
#pragma unroll
      for (int jj = 0; jj < 4; jj++)
        r2[wr * 64 + m * 16 + rowoff + jj][wc * 64 + n * 16 + rb] = f2bf(v[jj]);
    }
  __syncthreads();
  {
    const int row = tid >> 1, colE = (tid & 1) * 64;
    ushort* op = &outp[(size_t)(rowbase + row) * DHID + colbase + colE];
#pragma unroll
    for (int q = 0; q < 8; q++)
      *(uint4*)(op + q * 8) = *(const uint4*)&r2[row][colE + q * 8];
  }
}

// ---------------- combine: out[t] = ds[t] + dr[es1] + dr[es2]  (f32 out) ----------------
__global__ __launch_bounds__(256) void k_comb(
    const ushort* __restrict__ ds, const ushort* __restrict__ dr,
    const int* __restrict__ tslot, float* __restrict__ out)
{
  const int tid = threadIdx.x;
  const int t = blockIdx.x * 2 + (tid >> 7);
  const int d = (tid & 127) * 8;
  const int es1 = tslot[t * 2], es2 = tslot[t * 2 + 1];
  uint4 a = *(const uint4*)&ds[(size_t)t * DHID + d];
  float r[8];
  const ushort* ap = (const ushort*)&a;
#pragma unroll
  for (int k = 0; k < 8; ++k) r[k] = bf2f(ap[k]);
  if (es1 >= 0) {
    uint4 b = *(const uint4*)&dr[(size_t)es1 * DHID + d];
    const ushort* bp = (const ushort*)&b;
#pragma unroll
    for (int k = 0; k < 8; ++k) r[k] += bf2f(bp[k]);
  }
  if (es2 >= 0) {
    uint4 b = *(const uint4*)&dr[(size_t)es2 * DHID + d];
    const ushort* bp = (const ushort*)&b;
#pragma unroll
    for (int k = 0; k < 8; ++k) r[k] += bf2f(bp[k]);
  }
  float4* op = (float4*)&out[(size_t)t * DHID + d];
  op[0] = make_float4(r[0], r[1], r[2], r[3]);
  op[1] = make_float4(r[4], r[5], r[6], r[7]);
}

extern "C" void kernel_launch(void* const* d_in, const int* in_sizes, int n_in,
                              void* d_out, int out_size, void* d_ws, size_t ws_size,
                              hipStream_t stream) {
  const float* x    = (const float*)d_in[0];
  const float* rw   = (const float*)d_in[1];
  const float* wg_r = (const float*)d_in[2];
  const float* wu_r = (const float*)d_in[3];
  const float* wd_r = (const float*)d_in[4];
  const float* wg_s = (const float*)d_in[5];
  const float* wu_s = (const float*)d_in[6];
  const float* wd_s = (const float*)d_in[7];
  float* out = (float*)d_out;

  char* ws = (char*)d_ws;
  size_t off = 0;
  ushort* xb    = (ushort*)(ws + off); off += (size_t)T_TOK * DHID * 2;        // 4 MB
  ushort* wguTs = (ushort*)(ws + off); off += (size_t)2048 * DHID * 2;         // 4 MB  interleaved g/u rows
  ushort* wdTs  = (ushort*)(ws + off); off += (size_t)DHID * DHID * 2;         // 2 MB
  ushort* wguTr = (ushort*)(ws + off); off += (size_t)NEXP * 512 * DHID * 2;   // 16 MB interleaved per expert
  ushort* wdTr  = (ushort*)(ws + off); off += (size_t)NEXP * DHID * MR * 2;    // 8 MB
  ushort* h_s   = (ushort*)(ws + off); off += (size_t)T_TOK * DHID * 2;        // 4 MB
  ushort* h_r   = (ushort*)(ws + off); off += (size_t)NEXP * CAP * MR * 2;     // 4 MB
  ushort* ds    = (ushort*)(ws + off); off += (size_t)T_TOK * DHID * 2;        // 4 MB
  ushort* dr    = (ushort*)(ws + off); off += (size_t)NEXP * CAP * DHID * 2;   // 16 MB
  int*    cnt   = (int*)(ws + off);    off += 256;
  int*    ltok  = (int*)(ws + off);    off += (size_t)NEXP * CAP * 4;
  float*  lw    = (float*)(ws + off);  off += (size_t)NEXP * CAP * 4;
  int*    topi  = (int*)(ws + off);    off += (size_t)T_TOK * 4;
  float2* topw  = (float2*)(ws + off); off += (size_t)T_TOK * 8;
  int*    tslot = (int*)(ws + off);    off += (size_t)T_TOK * 2 * 4;
  if (off > ws_size) return;

  TP t0 = {wg_r, wguTr,             DHID, MR,   DHID, 1, (long long)512 * DHID};
  TP t1 = {wu_r, wguTr + 16 * DHID, DHID, MR,   DHID, 1, (long long)512 * DHID};
  TP t2 = {wg_s, wguTs,             DHID, MS,   DHID, 1, (long long)1024 * DHID};
  TP t3 = {wu_s, wguTs + 16 * DHID, DHID, MS,   DHID, 1, (long long)1024 * DHID};
  TP t4 = {wd_r, wdTr,              MR,   DHID, MR,   0, (long long)DHID * MR};
  TP t5 = {wd_s, wdTs,              MS,   DHID, DHID, 0, (long long)MS};

  k_prep<<<T_TOK / 8, 256, 0, stream>>>(x, rw, xb, topi, topw);
  k_build_tp<<<NEXP + 2560, 256, 0, stream>>>(topi, topw, cnt, ltok, lw, tslot, t0, t1, t2, t3);
  k_up<<<512 + 1280, 256, 0, stream>>>(xb, wguTs, wguTr, cnt, ltok, lw, h_s, h_r, t4, t5);
  k_down<<<640, 256, 0, stream>>>(h_s, wdTs, h_r, wdTr, cnt, ds, dr);
  k_comb<<<T_TOK / 2, 256, 0, stream>>>(ds, dr, tslot, out);
}

// Round 19
// 83.575 us; speedup vs baseline: 1.0049x; 1.0049x over previous
//
#include <hip/hip_runtime.h>
#include <hip/hip_bf16.h>
#include <stdint.h>

#define T_TOK 2048
#define DHID  1024
#define NEXP  16
#define MR    256
#define MS    512
#define CAP   512

typedef float  f32x4  __attribute__((ext_vector_type(4)));
typedef __bf16 bf16x8 __attribute__((ext_vector_type(8)));

typedef __attribute__((address_space(3))) void       lds_void;
typedef const __attribute__((address_space(1))) void gbl_void;

#define GLOAD16(g, l) __builtin_amdgcn_global_load_lds((gbl_void*)(g), (lds_void*)(l), 16, 0, 0)
#define VMCNT8() asm volatile("s_waitcnt vmcnt(8)" ::: "memory")
#define VMCNT0() asm volatile("s_waitcnt vmcnt(0)" ::: "memory")
#define SCHED_FENCE() __builtin_amdgcn_sched_barrier(0)

__device__ __forceinline__ void barrier_raw() {
  asm volatile("" ::: "memory");
  __builtin_amdgcn_s_barrier();
  asm volatile("" ::: "memory");
}

__device__ __forceinline__ ushort f2bf(float f) {
  uint32_t u = __float_as_uint(f);
  u = (u + 0x7fffu + ((u >> 16) & 1u)) >> 16;
  return (ushort)u;
}
__device__ __forceinline__ float bf2f(ushort v) { return __uint_as_float(((uint32_t)v) << 16); }

// ---- T2 staging: linear LDS dest, PRE-SWIZZLED global source column (rule #21) ----
__device__ __forceinline__ void stage128(const ushort* __restrict__ g0, int strideE,
                                         ushort* lds, int tid) {
  const int wave = tid >> 6;
  const int r = tid >> 3, colE = (tid & 7) * 8;
#pragma unroll
  for (int s = 0; s < 4; ++s) {
    const int row = s * 32 + r;
    GLOAD16(g0 + (size_t)row * strideE + (colE ^ ((row & 7) << 3)), lds + s * 2048 + wave * 512);
  }
}

__device__ __forceinline__ void stage_gather128(const ushort* __restrict__ xb,
                                                const int tok[4], int k0,
                                                ushort* lds, int tid) {
  const int wave = tid >> 6;
  const int r = tid >> 3, colE = (tid & 7) * 8;
#pragma unroll
  for (int s = 0; s < 4; ++s) {
    const int row = s * 32 + r;
    GLOAD16(xb + (size_t)tok[s] * DHID + k0 + (colE ^ ((row & 7) << 3)), lds + s * 2048 + wave * 512);
  }
}

// ---- one BK=64 step of the 128x128 tile, XOR-swizzled ds_read (conflict-free) ----
// T5: setprio(1) around the MFMA cluster
__device__ __forceinline__ void mfma_tile(const ushort* a_sh, const ushort* b_sh,
                                          int wr, int wc, int lane, f32x4 (&acc)[4][4]) {
  const int rb = lane & 15;
  const int sw = (rb & 7) << 3;
  __builtin_amdgcn_s_setprio(1);
#pragma unroll
  for (int kk = 0; kk < 64; kk += 32) {
    const int k8 = (kk + ((lane >> 4) << 3)) ^ sw;
    bf16x8 af[4];
#pragma unroll
    for (int m = 0; m < 4; m++)
      af[m] = *(const bf16x8*)&a_sh[(wr * 64 + m * 16 + rb) * 64 + k8];
#pragma unroll
    for (int n = 0; n < 4; n++) {
      bf16x8 bf = *(const bf16x8*)&b_sh[(wc * 64 + n * 16 + rb) * 64 + k8];
#pragma unroll
      for (int m = 0; m < 4; m++)
        acc[m][n] = __builtin_amdgcn_mfma_f32_16x16x32_bf16(af[m], bf, acc[m][n], 0, 0, 0);
    }
  }
  __builtin_amdgcn_s_setprio(0);
}

// ---- routed M-tile lookup from cnt[]: mti -> (e, s0, c) ----
__device__ __forceinline__ bool queue_lookup(const int* __restrict__ cnt, int mti,
                                             int& e_out, int& s0_out, int& c_out) {
  int acc = 0;
#pragma unroll
  for (int ee = 0; ee < NEXP; ++ee) {
    const int c = cnt[ee];
    const int ntl = (c + 127) >> 7;
    if (mti < acc + ntl) { e_out = ee; s0_out = (mti - acc) << 7; c_out = c; return true; }
    acc += ntl;
  }
  return false;
}

// ---------------- transpose tile worker ----------------
struct TP {
  const float* in; ushort* out;
  int R, C, out_ld, ilv;
  long long out_batch;
};

__device__ __forceinline__ void tpose_tile(const TP p, int local, void* smem, int tid) {
  float (*t_sh)[65] = (float(*)[65])smem;
  const int tr = p.R >> 6, tc = p.C >> 6, per = tr * tc;
  const int b = local / per, rem = local - b * per;
  const int rt = rem / tc, ct = rem - rt * tc;
  const int r0 = rt * 64, c0 = ct * 64;
  const float* ip = p.in + (size_t)b * p.R * p.C;
  ushort* op = p.out + (size_t)b * p.out_batch;
  const int trd = tid >> 4, tcd = (tid & 15) * 4;
#pragma unroll
  for (int q = 0; q < 4; q++) {
    float4 v = *(const float4*)&ip[(size_t)(r0 + trd + q * 16) * p.C + c0 + tcd];
    t_sh[trd + q * 16][tcd + 0] = v.x; t_sh[trd + q * 16][tcd + 1] = v.y;
    t_sh[trd + q * 16][tcd + 2] = v.z; t_sh[trd + q * 16][tcd + 3] = v.w;
  }
  __syncthreads();
#pragma unroll
  for (int q = 0; q < 4; q++) {
    const int cc = trd + q * 16;
    int rr = c0 + cc;
    if (p.ilv) rr = ((rr >> 4) << 5) + (rr & 15);   // 16-row g/u interleave slot
    ushort4 o;
    o.x = f2bf(t_sh[tcd + 0][cc]); o.y = f2bf(t_sh[tcd + 1][cc]);
    o.z = f2bf(t_sh[tcd + 2][cc]); o.w = f2bf(t_sh[tcd + 3][cc]);
    *(ushort4*)&op[(size_t)rr * p.out_ld + r0 + tcd] = o;
  }
}

// ---------------- k_prep: x->bf16 + fp32 router; 16 tokens per block ----------------
__global__ __launch_bounds__(256) void k_prep(
    const float* __restrict__ x, const float* __restrict__ rw,
    ushort* __restrict__ xb, int* __restrict__ topi, float2* __restrict__ topw)
{
  __shared__ float rw_sh[NEXP][DHID];   // 64 KB, transposed [e][d]
  const int tid = threadIdx.x;
#pragma unroll
  for (int it = 0; it < 16; ++it) {
    const int flat = it * 1024 + tid * 4;
    float4 v = *(const float4*)&rw[flat];
    const int d = flat >> 4, e = flat & 15;
    rw_sh[e + 0][d] = v.x; rw_sh[e + 1][d] = v.y;
    rw_sh[e + 2][d] = v.z; rw_sh[e + 3][d] = v.w;
  }
  __syncthreads();

  const int wave = tid >> 6, lane = tid & 63;
  for (int tk = 0; tk < 4; ++tk) {
    const int t = blockIdx.x * 16 + wave * 4 + tk;
    const float* xp = x + (size_t)t * DHID;
    float acc[NEXP];
#pragma unroll
    for (int e = 0; e < NEXP; e++) acc[e] = 0.f;
#pragma unroll
    for (int i = 0; i < 4; ++i) {
      const int d4 = i * 64 + lane;
      float4 xv = *(const float4*)&xp[d4 * 4];
      ushort4 o; o.x = f2bf(xv.x); o.y = f2bf(xv.y); o.z = f2bf(xv.z); o.w = f2bf(xv.w);
      *(ushort4*)&xb[(size_t)t * DHID + d4 * 4] = o;
#pragma unroll
      for (int e = 0; e < NEXP; e++) {
        float4 wv = *(const float4*)&rw_sh[e][d4 * 4];
        acc[e] = fmaf(xv.x, wv.x, acc[e]);
        acc[e] = fmaf(xv.y, wv.y, acc[e]);
        acc[e] = fmaf(xv.z, wv.z, acc[e]);
        acc[e] = fmaf(xv.w, wv.w, acc[e]);
      }
    }
#pragma unroll
    for (int off = 32; off >= 1; off >>= 1) {
#pragma unroll
      for (int e = 0; e < NEXP; e++) acc[e] += __shfl_xor(acc[e], off, 64);
    }
    if (lane == 0) {
      float m = acc[0];
#pragma unroll
      for (int e = 1; e < NEXP; e++) m = fmaxf(m, acc[e]);
      float p[NEXP], Z = 0.f;
#pragma unroll
      for (int e = 0; e < NEXP; e++) { p[e] = __expf(acc[e] - m); Z += p[e]; }
      const float inv = 1.f / Z;
      int i1 = 0; float p1 = p[0] * inv;
      for (int e = 1; e < NEXP; e++) { float pe = p[e] * inv; if (pe > p1) { p1 = pe; i1 = e; } }
      int i2 = -1; float p2 = -1.f;
      for (int e = 0; e < NEXP; e++) { if (e == i1) continue; float pe = p[e] * inv; if (pe > p2) { p2 = pe; i2 = e; } }
      const float denom = p1 + p2 + 1e-9f;
      topi[t] = i1 | (i2 << 8);
      topw[t] = make_float2(p1 / denom, p2 / denom);
    }
  }
}

// ---------------- k_build (blocks 0..15) + wgu transposes (2560 blocks) ----------------
__global__ __launch_bounds__(256) void k_build_tp(
    const int* __restrict__ topi, const float2* __restrict__ topw,
    int* __restrict__ cnt, int* __restrict__ ltok, float* __restrict__ lw,
    int* __restrict__ tslot, TP t0, TP t1, TP t2, TP t3)
{
  __shared__ float t_smem[64][65];     // 16.6 KB
  const int tid = threadIdx.x;
  const int bid = blockIdx.x;
  if (bid >= NEXP) {
    const int local = bid - NEXP;
    if      (local < 1024) tpose_tile(t0, local,        t_smem, tid);
    else if (local < 2048) tpose_tile(t1, local - 1024, t_smem, tid);
    else if (local < 2304) tpose_tile(t2, local - 2048, t_smem, tid);
    else                   tpose_tile(t3, local - 2304, t_smem, tid);
    return;
  }
  int* wsum = (int*)t_smem;
  const int e = bid;
  const int wave = tid >> 6, lane = tid & 63;
  const int t0i = tid * 8;

  int4 a = *(const int4*)&topi[t0i];
  int4 b = *(const int4*)&topi[t0i + 4];
  int ti[8] = {a.x, a.y, a.z, a.w, b.x, b.y, b.z, b.w};
  int match[8]; int c = 0;
#pragma unroll
  for (int k = 0; k < 8; ++k) {
    const int i1 = ti[k] & 0xff, i2 = (ti[k] >> 8) & 0xff;
    match[k] = (i1 == e) ? 1 : ((i2 == e) ? 2 : 0);
    c += (match[k] != 0);
  }
  int incl = c;
#pragma unroll
  for (int off = 1; off < 64; off <<= 1) {
    int n = __shfl_up(incl, off, 64);
    if (lane >= off) incl += n;
  }
  if (lane == 63) wsum[wave] = incl;
  __syncthreads();
  int base = incl - c;
  for (int w = 0; w < wave; ++w) base += wsum[w];
  if (tid == 0) {
    int tot = wsum[0] + wsum[1] + wsum[2] + wsum[3];
    cnt[e] = tot > CAP ? CAP : tot;
  }
#pragma unroll
  for (int k = 0; k < 8; ++k) {
    if (match[k]) {
      const int t = t0i + k;
      if (base < CAP) {
        float2 w2 = topw[t];
        ltok[e * CAP + base] = t;
        lw[e * CAP + base] = (match[k] == 1) ? w2.x : w2.y;
        tslot[t * 2 + (match[k] - 1)] = e * CAP + base;
      } else {
        tslot[t * 2 + (match[k] - 1)] = -1;
      }
      base++;
    }
  }
}

// ---------------- k_up: up GEMMs (512, T4 counted-vmcnt dbuf, sched-fenced) + wd tposes ----------------
__global__ __launch_bounds__(256) void k_up(
    const ushort* __restrict__ xb, const ushort* __restrict__ wguTs,
    const ushort* __restrict__ wguTr, const int* __restrict__ cnt,
    const int* __restrict__ ltok, const float* __restrict__ lw,
    ushort* __restrict__ h_s, ushort* __restrict__ h_r, TP t4, TP t5)
{
  __shared__ ushort smem[4 * 128 * 64];        // 64 KB: A0 | A1 | B0 | B1
  ushort (*r_sh)[64] = (ushort(*)[64])smem;    // 16 KB epilogue alias
  const int tid = threadIdx.x, lane = tid & 63, wave = tid >> 6;
  const int wr = wave >> 1, wc = wave & 1;
  const int rb = lane & 15, rowoff = (lane >> 4) << 2;
  const int bid0 = blockIdx.x;
  if (bid0 >= 512) {
    const int local = bid0 - 512;
    if (local < 1024) tpose_tile(t4, local, smem, tid);
    else              tpose_tile(t5, local - 1024, smem, tid);
    return;
  }
  f32x4 acc[4][4] = {};

  if (bid0 < 256) {
    const int bid = (bid0 & 7) * 32 + (bid0 >> 3);   // bijective swizzle within [0,256)
    const int mt = bid & 15, nt = bid >> 4;
    const ushort* Ab = xb + (size_t)mt * 128 * DHID;
    const ushort* Bb = wguTs + (size_t)nt * 128 * DHID;
    stage128(Ab, DHID, smem, tid);
    stage128(Bb, DHID, smem + 16384, tid);
    for (int t = 0; t < 16; ++t) {
      const int co = (t & 1) * 8192;
      const int no = ((t + 1) & 1) * 8192;
      if (t < 15) {
        stage128(Ab + (t + 1) * 64, DHID, smem + no, tid);
        stage128(Bb + (t + 1) * 64, DHID, smem + 16384 + no, tid);
        SCHED_FENCE();           // pin stage loads above the counted wait
        VMCNT8();
      } else {
        SCHED_FENCE();
        VMCNT0();
      }
      SCHED_FENCE();
      barrier_raw();
      SCHED_FENCE();             // ds_reads stay below barrier#1
      mfma_tile(smem + co, smem + 16384 + co, wr, wc, lane, acc);
      SCHED_FENCE();             // ds_reads stay above barrier#2
      barrier_raw();
    }
#pragma unroll
    for (int m = 0; m < 4; m++)
#pragma unroll
      for (int p = 0; p < 2; p++) {
        f32x4 g = acc[m][2 * p], u = acc[m][2 * p + 1];
#pragma unroll
        for (int jj = 0; jj < 4; jj++) {
          float gv = g[jj];
          float hv = (gv / (1.f + __expf(-gv))) * u[jj];
          r_sh[wr * 64 + m * 16 + rowoff + jj][wc * 32 + p * 16 + rb] = f2bf(hv);
        }
      }
    __syncthreads();
#pragma unroll
    for (int sp = 0; sp < 4; sp++) {
      const int row = sp * 32 + (tid >> 3), col = (tid & 7) * 8;
      *(uint4*)&h_s[(size_t)(mt * 128 + row) * DHID + nt * 64 + col] = *(const uint4*)&r_sh[row][col];
    }
  } else {
    const int id = bid0 - 256;                 // round-robin spreads dead blocks
    const int mti = id >> 2, ntile = id & 3;
    int e, s0, c;
    if (!queue_lookup(cnt, mti, e, s0, c)) return;
    int tok[4];
#pragma unroll
    for (int s = 0; s < 4; ++s) {
      int slot = s0 + s * 32 + (tid >> 3);
      if (slot >= c) slot = c - 1;
      tok[s] = ltok[e * CAP + slot];
    }
    const ushort* Bb = wguTr + ((size_t)e * 512 + ntile * 128) * DHID;
    stage_gather128(xb, tok, 0, smem, tid);
    stage128(Bb, DHID, smem + 16384, tid);
    for (int t = 0; t < 16; ++t) {
      const int co = (t & 1) * 8192;
      const int no = ((t + 1) & 1) * 8192;
      if (t < 15) {
        stage_gather128(xb, tok, (t + 1) * 64, smem + no, tid);
        stage128(Bb + (t + 1) * 64, DHID, smem + 16384 + no, tid);
        SCHED_FENCE();
        VMCNT8();
      } else {
        SCHED_FENCE();
        VMCNT0();
      }
      SCHED_FENCE();
      barrier_raw();
      SCHED_FENCE();
      mfma_tile(smem + co, smem + 16384 + co, wr, wc, lane, acc);
      SCHED_FENCE();
      barrier_raw();
    }
#pragma unroll
    for (int m = 0; m < 4; m++)
#pragma unroll
      for (int jj = 0; jj < 4; jj++) {
        const int slot = s0 + wr * 64 + m * 16 + rowoff + jj;
        const float w = (slot < c) ? lw[e * CAP + slot] : 0.f;
#pragma unroll
        for (int p = 0; p < 2; p++) {
          float gv = acc[m][2 * p][jj];
          float hv = (gv / (1.f + __expf(-gv))) * acc[m][2 * p + 1][jj] * w;
          r_sh[wr * 64 + m * 16 + rowoff + jj][wc * 32 + p * 16 + rb] = f2bf(hv);
        }
      }
    __syncthreads();
#pragma unroll
    for (int sp = 0; sp < 4; sp++) {
      const int row = sp * 32 + (tid >> 3), col = (tid & 7) * 8;
      *(uint4*)&h_r[((size_t)e * CAP + s0 + row) * MR + ntile * 64 + col] = *(const uint4*)&r_sh[row][col];
    }
  }
}

// ---------------- k_down: merged down GEMMs (T4 counted-vmcnt dbuf, sched-fenced) ----------------
__global__ __launch_bounds__(256) void k_down(
    const ushort* __restrict__ h_s, const ushort* __restrict__ wdTs,
    const ushort* __restrict__ h_r, const ushort* __restrict__ wdTr,
    const int* __restrict__ cnt, ushort* __restrict__ ds, ushort* __restrict__ dr)
{
  __shared__ ushort smem[4 * 128 * 64];          // 64 KB
  ushort (*r2)[128] = (ushort(*)[128])smem;
  const int tid = threadIdx.x, lane = tid & 63, wave = tid >> 6;
  const int wr = wave >> 1, wc = wave & 1;
  const int rb = lane & 15, rowoff = (lane >> 4) << 2;
  f32x4 acc[4][4] = {};
  const int bid0 = blockIdx.x;

  const ushort* Ab; const ushort* Bb;
  int K, rowbase, colbase; ushort* outp;
  if (bid0 < 128) {
    const int bid = (bid0 & 7) * 16 + (bid0 >> 3);   // bijective swizzle within [0,128)
    const int mt = bid >> 3, nt = bid & 7;
    Ab = h_s + (size_t)mt * 128 * DHID;
    Bb = wdTs + (size_t)nt * 128 * DHID;
    K = DHID; rowbase = mt * 128; colbase = nt * 128;
    outp = ds;
  } else {
    const int id = bid0 - 128;
    const int mti = id >> 3, nt = id & 7;
    int e, s0, c;
    if (!queue_lookup(cnt, mti, e, s0, c)) return;
    Ab = h_r + ((size_t)e * CAP + s0) * MR;
    Bb = wdTr + ((size_t)e * DHID + nt * 128) * MR;
    K = MR; rowbase = e * CAP + s0; colbase = nt * 128;
    outp = dr;
  }
  const int nk = K >> 6;
  stage128(Ab, K, smem, tid);
  stage128(Bb, K, smem + 16384, tid);
  for (int t = 0; t < nk; ++t) {
    const int co = (t & 1) * 8192;
    const int no = ((t + 1) & 1) * 8192;
    if (t + 1 < nk) {
      stage128(Ab + (t + 1) * 64, K, smem + no, tid);
      stage128(Bb + (t + 1) * 64, K, smem + 16384 + no, tid);
      SCHED_FENCE();
      VMCNT8();
    } else {
      SCHED_FENCE();
      VMCNT0();
    }
    SCHED_FENCE();
    barrier_raw();
    SCHED_FENCE();
    mfma_tile(smem + co, smem + 16384 + co, wr, wc, lane, acc);
    SCHED_FENCE();
    barrier_raw();
  }
#pragma unroll
  for (int m = 0; m < 4; m++)
#pragma unroll
    for (int n = 0; n < 4; n++) {
      f32x4 v = acc[m][n];
#pragma unroll
      for (int jj = 0; jj < 4; jj++)
        r2[wr * 64 + m * 16 + rowoff + jj][wc * 64 + n * 16 + rb] = f2bf(v[jj]);
    }
  __syncthreads();
  {
    const int row = tid >> 1, colE = (tid & 1) * 64;
    ushort* op = &outp[(size_t)(rowbase + row) * DHID + colbase + colE];
#pragma unroll
    for (int q = 0; q < 8; q++)
      *(uint4*)(op + q * 8) = *(const uint4*)&r2[row][colE + q * 8];
  }
}

// ---------------- combine: out[t] = ds[t] + dr[es1] + dr[es2]  (f32 out) ----------------
__global__ __launch_bounds__(256) void k_comb(
    const ushort* __restrict__ ds, const ushort* __restrict__ dr,
    const int* __restrict__ tslot, float* __restrict__ out)
{
  const int tid = threadIdx.x;
  const int t = blockIdx.x * 2 + (tid >> 7);
  const int d = (tid & 127) * 8;
  const int es1 = tslot[t * 2], es2 = tslot[t * 2 + 1];
  uint4 a = *(const uint4*)&ds[(size_t)t * DHID + d];
  float r[8];
  const ushort* ap = (const ushort*)&a;
#pragma unroll
  for (int k = 0; k < 8; ++k) r[k] = bf2f(ap[k]);
  if (es1 >= 0) {
    uint4 b = *(const uint4*)&dr[(size_t)es1 * DHID + d];
    const ushort* bp = (const ushort*)&b;
#pragma unroll
    for (int k = 0; k < 8; ++k) r[k] += bf2f(bp[k]);
  }
  if (es2 >= 0) {
    uint4 b = *(const uint4*)&dr[(size_t)es2 * DHID + d];
    const ushort* bp = (const ushort*)&b;
#pragma unroll
    for (int k = 0; k < 8; ++k) r[k] += bf2f(bp[k]);
  }
  float4* op = (float4*)&out[(size_t)t * DHID + d];
  op[0] = make_float4(r[0], r[1], r[2], r[3]);
  op[1] = make_float4(r[4], r[5], r[6], r[7]);
}

extern "C" void kernel_launch(void* const* d_in, const int* in_sizes, int n_in,
                              void* d_out, int out_size, void* d_ws, size_t ws_size,
                              hipStream_t stream) {
  const float* x    = (const float*)d_in[0];
  const float* rw   = (const float*)d_in[1];
  const float* wg_r = (const float*)d_in[2];
  const float* wu_r = (const float*)d_in[3];
  const float* wd_r = (const float*)d_in[4];
  const float* wg_s = (const float*)d_in[5];
  const float* wu_s = (const float*)d_in[6];
  const float* wd_s = (const float*)d_in[7];
  float* out = (float*)d_out;

  char* ws = (char*)d_ws;
  size_t off = 0;
  ushort* xb    = (ushort*)(ws + off); off += (size_t)T_TOK * DHID * 2;        // 4 MB
  ushort* wguTs = (ushort*)(ws + off); off += (size_t)2048 * DHID * 2;         // 4 MB  interleaved g/u rows
  ushort* wdTs  = (ushort*)(ws + off); off += (size_t)DHID * DHID * 2;         // 2 MB
  ushort* wguTr = (ushort*)(ws + off); off += (size_t)NEXP * 512 * DHID * 2;   // 16 MB interleaved per expert
  ushort* wdTr  = (ushort*)(ws + off); off += (size_t)NEXP * DHID * MR * 2;    // 8 MB
  ushort* h_s   = (ushort*)(ws + off); off += (size_t)T_TOK * DHID * 2;        // 4 MB
  ushort* h_r   = (ushort*)(ws + off); off += (size_t)NEXP * CAP * MR * 2;     // 4 MB
  ushort* ds    = (ushort*)(ws + off); off += (size_t)T_TOK * DHID * 2;        // 4 MB
  ushort* dr    = (ushort*)(ws + off); off += (size_t)NEXP * CAP * DHID * 2;   // 16 MB
  int*    cnt   = (int*)(ws + off);    off += 256;
  int*    ltok  = (int*)(ws + off);    off += (size_t)NEXP * CAP * 4;
  float*  lw    = (float*)(ws + off);  off += (size_t)NEXP * CAP * 4;
  int*    topi  = (int*)(ws + off);    off += (size_t)T_TOK * 4;
  float2* topw  = (float2*)(ws + off); off += (size_t)T_TOK * 8;
  int*    tslot = (int*)(ws + off);    off += (size_t)T_TOK * 2 * 4;
  if (off > ws_size) return;

  TP t0 = {wg_r, wguTr,             DHID, MR,   DHID, 1, (long long)512 * DHID};
  TP t1 = {wu_r, wguTr + 16 * DHID, DHID, MR,   DHID, 1, (long long)512 * DHID};
  TP t2 = {wg_s, wguTs,             DHID, MS,   DHID, 1, (long long)1024 * DHID};
  TP t3 = {wu_s, wguTs + 16 * DHID, DHID, MS,   DHID, 1, (long long)1024 * DHID};
  TP t4 = {wd_r, wdTr,              MR,   DHID, MR,   0, (long long)DHID * MR};
  TP t5 = {wd_s, wdTs,              MS,   DHID, DHID, 0, (long long)MS};

  k_prep<<<T_TOK / 16, 256, 0, stream>>>(x, rw, xb, topi, topw);
  k_build_tp<<<NEXP + 2560, 256, 0, stream>>>(topi, topw, cnt, ltok, lw, tslot, t0, t1, t2, t3);
  k_up<<<512 + 1280, 256, 0, stream>>>(xb, wguTs, wguTr, cnt, ltok, lw, h_s, h_r, t4, t5);
  k_down<<<640, 256, 0, stream>>>(h_s, wdTs, h_r, wdTr, cnt, ds, dr);
  k_comb<<<T_TOK / 2, 256, 0, stream>>>(ds, dr, tslot, out);
}

// Round 20
// 75.567 us; speedup vs baseline: 1.1114x; 1.1060x over previous
//
#include <hip/hip_runtime.h>
#include <hip/hip_bf16.h>
#include <stdint.h>

#define T_TOK 2048
#define DHID  1024
#define NEXP  16
#define MR    256
#define MS    512
#define CAP   512

typedef float  f32x4  __attribute__((ext_vector_type(4)));
typedef __bf16 bf16x8 __attribute__((ext_vector_type(8)));

typedef __attribute__((address_space(3))) void       lds_void;
typedef const __attribute__((address_space(1))) void gbl_void;

#define GLOAD16(g, l) __builtin_amdgcn_global_load_lds((gbl_void*)(g), (lds_void*)(l), 16, 0, 0)
#define VMCNT8() asm volatile("s_waitcnt vmcnt(8)" ::: "memory")
#define VMCNT0() asm volatile("s_waitcnt vmcnt(0)" ::: "memory")
#define SCHED_FENCE() __builtin_amdgcn_sched_barrier(0)

__device__ __forceinline__ void barrier_raw() {
  asm volatile("" ::: "memory");
  __builtin_amdgcn_s_barrier();
  asm volatile("" ::: "memory");
}

__device__ __forceinline__ ushort f2bf(float f) {
  uint32_t u = __float_as_uint(f);
  u = (u + 0x7fffu + ((u >> 16) & 1u)) >> 16;
  return (ushort)u;
}
__device__ __forceinline__ float bf2f(ushort v) { return __uint_as_float(((uint32_t)v) << 16); }

// ---- T2 staging: linear LDS dest, PRE-SWIZZLED global source column (rule #21) ----
__device__ __forceinline__ void stage128(const ushort* __restrict__ g0, int strideE,
                                         ushort* lds, int tid) {
  const int wave = tid >> 6;
  const int r = tid >> 3, colE = (tid & 7) * 8;
#pragma unroll
  for (int s = 0; s < 4; ++s) {
    const int row = s * 32 + r;
    GLOAD16(g0 + (size_t)row * strideE + (colE ^ ((row & 7) << 3)), lds + s * 2048 + wave * 512);
  }
}

__device__ __forceinline__ void stage_gather128(const ushort* __restrict__ xb,
                                                const int tok[4], int k0,
                                                ushort* lds, int tid) {
  const int wave = tid >> 6;
  const int r = tid >> 3, colE = (tid & 7) * 8;
#pragma unroll
  for (int s = 0; s < 4; ++s) {
    const int row = s * 32 + r;
    GLOAD16(xb + (size_t)tok[s] * DHID + k0 + (colE ^ ((row & 7) << 3)), lds + s * 2048 + wave * 512);
  }
}

// ---- one BK=64 step of the 128x128 tile, XOR-swizzled ds_read (conflict-free) ----
// T5: setprio(1) around the MFMA cluster
__device__ __forceinline__ void mfma_tile(const ushort* a_sh, const ushort* b_sh,
                                          int wr, int wc, int lane, f32x4 (&acc)[4][4]) {
  const int rb = lane & 15;
  const int sw = (rb & 7) << 3;
  __builtin_amdgcn_s_setprio(1);
#pragma unroll
  for (int kk = 0; kk < 64; kk += 32) {
    const int k8 = (kk + ((lane >> 4) << 3)) ^ sw;
    bf16x8 af[4];
#pragma unroll
    for (int m = 0; m < 4; m++)
      af[m] = *(const bf16x8*)&a_sh[(wr * 64 + m * 16 + rb) * 64 + k8];
#pragma unroll
    for (int n = 0; n < 4; n++) {
      bf16x8 bf = *(const bf16x8*)&b_sh[(wc * 64 + n * 16 + rb) * 64 + k8];
#pragma unroll
      for (int m = 0; m < 4; m++)
        acc[m][n] = __builtin_amdgcn_mfma_f32_16x16x32_bf16(af[m], bf, acc[m][n], 0, 0, 0);
    }
  }
  __builtin_amdgcn_s_setprio(0);
}

// ---- routed M-tile lookup from cnt[]: mti -> (e, s0, c) ----
__device__ __forceinline__ bool queue_lookup(const int* __restrict__ cnt, int mti,
                                             int& e_out, int& s0_out, int& c_out) {
  int acc = 0;
#pragma unroll
  for (int ee = 0; ee < NEXP; ++ee) {
    const int c = cnt[ee];
    const int ntl = (c + 127) >> 7;
    if (mti < acc + ntl) { e_out = ee; s0_out = (mti - acc) << 7; c_out = c; return true; }
    acc += ntl;
  }
  return false;
}

// ---------------- transpose tile worker ----------------
struct TP {
  const float* in; ushort* out;
  int R, C, out_ld, ilv;
  long long out_batch;
};

__device__ __forceinline__ void tpose_tile(const TP p, int local, void* smem, int tid) {
  float (*t_sh)[65] = (float(*)[65])smem;
  const int tr = p.R >> 6, tc = p.C >> 6, per = tr * tc;
  const int b = local / per, rem = local - b * per;
  const int rt = rem / tc, ct = rem - rt * tc;
  const int r0 = rt * 64, c0 = ct * 64;
  const float* ip = p.in + (size_t)b * p.R * p.C;
  ushort* op = p.out + (size_t)b * p.out_batch;
  const int trd = tid >> 4, tcd = (tid & 15) * 4;
#pragma unroll
  for (int q = 0; q < 4; q++) {
    float4 v = *(const float4*)&ip[(size_t)(r0 + trd + q * 16) * p.C + c0 + tcd];
    t_sh[trd + q * 16][tcd + 0] = v.x; t_sh[trd + q * 16][tcd + 1] = v.y;
    t_sh[trd + q * 16][tcd + 2] = v.z; t_sh[trd + q * 16][tcd + 3] = v.w;
  }
  __syncthreads();
#pragma unroll
  for (int q = 0; q < 4; q++) {
    const int cc = trd + q * 16;
    int rr = c0 + cc;
    if (p.ilv) rr = ((rr >> 4) << 5) + (rr & 15);   // 16-row g/u interleave slot
    ushort4 o;
    o.x = f2bf(t_sh[tcd + 0][cc]); o.y = f2bf(t_sh[tcd + 1][cc]);
    o.z = f2bf(t_sh[tcd + 2][cc]); o.w = f2bf(t_sh[tcd + 3][cc]);
    *(ushort4*)&op[(size_t)rr * p.out_ld + r0 + tcd] = o;
  }
}

// ---------------- k_prep: x->bf16 + fp32 router; 8 tokens per block ----------------
__global__ __launch_bounds__(256) void k_prep(
    const float* __restrict__ x, const float* __restrict__ rw,
    ushort* __restrict__ xb, int* __restrict__ topi, float2* __restrict__ topw)
{
  __shared__ float rw_sh[NEXP][DHID];   // 64 KB, transposed [e][d]
  const int tid = threadIdx.x;
#pragma unroll
  for (int it = 0; it < 16; ++it) {
    const int flat = it * 1024 + tid * 4;
    float4 v = *(const float4*)&rw[flat];
    const int d = flat >> 4, e = flat & 15;
    rw_sh[e + 0][d] = v.x; rw_sh[e + 1][d] = v.y;
    rw_sh[e + 2][d] = v.z; rw_sh[e + 3][d] = v.w;
  }
  __syncthreads();

  const int wave = tid >> 6, lane = tid & 63;
  for (int tk = 0; tk < 2; ++tk) {
    const int t = blockIdx.x * 8 + wave * 2 + tk;
    const float* xp = x + (size_t)t * DHID;
    float acc[NEXP];
#pragma unroll
    for (int e = 0; e < NEXP; e++) acc[e] = 0.f;
#pragma unroll
    for (int i = 0; i < 4; ++i) {
      const int d4 = i * 64 + lane;
      float4 xv = *(const float4*)&xp[d4 * 4];
      ushort4 o; o.x = f2bf(xv.x); o.y = f2bf(xv.y); o.z = f2bf(xv.z); o.w = f2bf(xv.w);
      *(ushort4*)&xb[(size_t)t * DHID + d4 * 4] = o;
#pragma unroll
      for (int e = 0; e < NEXP; e++) {
        float4 wv = *(const float4*)&rw_sh[e][d4 * 4];
        acc[e] = fmaf(xv.x, wv.x, acc[e]);
        acc[e] = fmaf(xv.y, wv.y, acc[e]);
        acc[e] = fmaf(xv.z, wv.z, acc[e]);
        acc[e] = fmaf(xv.w, wv.w, acc[e]);
      }
    }
#pragma unroll
    for (int off = 32; off >= 1; off >>= 1) {
#pragma unroll
      for (int e = 0; e < NEXP; e++) acc[e] += __shfl_xor(acc[e], off, 64);
    }
    if (lane == 0) {
      float m = acc[0];
#pragma unroll
      for (int e = 1; e < NEXP; e++) m = fmaxf(m, acc[e]);
      float p[NEXP], Z = 0.f;
#pragma unroll
      for (int e = 0; e < NEXP; e++) { p[e] = __expf(acc[e] - m); Z += p[e]; }
      const float inv = 1.f / Z;
      int i1 = 0; float p1 = p[0] * inv;
      for (int e = 1; e < NEXP; e++) { float pe = p[e] * inv; if (pe > p1) { p1 = pe; i1 = e; } }
      int i2 = -1; float p2 = -1.f;
      for (int e = 0; e < NEXP; e++) { if (e == i1) continue; float pe = p[e] * inv; if (pe > p2) { p2 = pe; i2 = e; } }
      const float denom = p1 + p2 + 1e-9f;
      topi[t] = i1 | (i2 << 8);
      topw[t] = make_float2(p1 / denom, p2 / denom);
    }
  }
}

// ---------------- k_build (blocks 0..15) + wgu transposes (2560 blocks) ----------------
__global__ __launch_bounds__(256) void k_build_tp(
    const int* __restrict__ topi, const float2* __restrict__ topw,
    int* __restrict__ cnt, int* __restrict__ ltok, float* __restrict__ lw,
    int* __restrict__ tslot, TP t0, TP t1, TP t2, TP t3)
{
  __shared__ float t_smem[64][65];     // 16.6 KB
  const int tid = threadIdx.x;
  const int bid = blockIdx.x;
  if (bid >= NEXP) {
    const int local = bid - NEXP;
    if      (local < 1024) tpose_tile(t0, local,        t_smem, tid);
    else if (local < 2048) tpose_tile(t1, local - 1024, t_smem, tid);
    else if (local < 2304) tpose_tile(t2, local - 2048, t_smem, tid);
    else                   tpose_tile(t3, local - 2304, t_smem, tid);
    return;
  }
  int* wsum = (int*)t_smem;
  const int e = bid;
  const int wave = tid >> 6, lane = tid & 63;
  const int t0i = tid * 8;

  int4 a = *(const int4*)&topi[t0i];
  int4 b = *(const int4*)&topi[t0i + 4];
  int ti[8] = {a.x, a.y, a.z, a.w, b.x, b.y, b.z, b.w};
  int match[8]; int c = 0;
#pragma unroll
  for (int k = 0; k < 8; ++k) {
    const int i1 = ti[k] & 0xff, i2 = (ti[k] >> 8) & 0xff;
    match[k] = (i1 == e) ? 1 : ((i2 == e) ? 2 : 0);
    c += (match[k] != 0);
  }
  int incl = c;
#pragma unroll
  for (int off = 1; off < 64; off <<= 1) {
    int n = __shfl_up(incl, off, 64);
    if (lane >= off) incl += n;
  }
  if (lane == 63) wsum[wave] = incl;
  __syncthreads();
  int base = incl - c;
  for (int w = 0; w < wave; ++w) base += wsum[w];
  if (tid == 0) {
    int tot = wsum[0] + wsum[1] + wsum[2] + wsum[3];
    cnt[e] = tot > CAP ? CAP : tot;
  }
#pragma unroll
  for (int k = 0; k < 8; ++k) {
    if (match[k]) {
      const int t = t0i + k;
      if (base < CAP) {
        float2 w2 = topw[t];
        ltok[e * CAP + base] = t;
        lw[e * CAP + base] = (match[k] == 1) ? w2.x : w2.y;
        tslot[t * 2 + (match[k] - 1)] = e * CAP + base;
      } else {
        tslot[t * 2 + (match[k] - 1)] = -1;
      }
      base++;
    }
  }
}

// ---------------- k_up: up GEMMs (512, T4 counted-vmcnt dbuf, sched-fenced) + wd tposes ----------------
__global__ __launch_bounds__(256) void k_up(
    const ushort* __restrict__ xb, const ushort* __restrict__ wguTs,
    const ushort* __restrict__ wguTr, const int* __restrict__ cnt,
    const int* __restrict__ ltok, const float* __restrict__ lw,
    ushort* __restrict__ h_s, ushort* __restrict__ h_r, TP t4, TP t5)
{
  __shared__ ushort smem[4 * 128 * 64];        // 64 KB: A0 | A1 | B0 | B1
  ushort (*r_sh)[64] = (ushort(*)[64])smem;    // 16 KB epilogue alias
  const int tid = threadIdx.x, lane = tid & 63, wave = tid >> 6;
  const int wr = wave >> 1, wc = wave & 1;
  const int rb = lane & 15, rowoff = (lane >> 4) << 2;
  const int bid0 = blockIdx.x;
  if (bid0 >= 512) {
    const int local = bid0 - 512;
    if (local < 1024) tpose_tile(t4, local, smem, tid);
    else              tpose_tile(t5, local - 1024, smem, tid);
    return;
  }
  f32x4 acc[4][4] = {};

  if (bid0 < 256) {
    const int bid = (bid0 & 7) * 32 + (bid0 >> 3);   // bijective swizzle within [0,256)
    const int mt = bid & 15, nt = bid >> 4;
    const ushort* Ab = xb + (size_t)mt * 128 * DHID;
    const ushort* Bb = wguTs + (size_t)nt * 128 * DHID;
    stage128(Ab, DHID, smem, tid);
    stage128(Bb, DHID, smem + 16384, tid);
    for (int t = 0; t < 16; ++t) {
      const int co = (t & 1) * 8192;
      const int no = ((t + 1) & 1) * 8192;
      if (t < 15) {
        stage128(Ab + (t + 1) * 64, DHID, smem + no, tid);
        stage128(Bb + (t + 1) * 64, DHID, smem + 16384 + no, tid);
        SCHED_FENCE();           // pin stage loads above the counted wait
        VMCNT8();
      } else {
        SCHED_FENCE();
        VMCNT0();
      }
      SCHED_FENCE();
      barrier_raw();
      SCHED_FENCE();             // ds_reads stay below barrier#1
      mfma_tile(smem + co, smem + 16384 + co, wr, wc, lane, acc);
      SCHED_FENCE();             // ds_reads stay above barrier#2
      barrier_raw();
    }
#pragma unroll
    for (int m = 0; m < 4; m++)
#pragma unroll
      for (int p = 0; p < 2; p++) {
        f32x4 g = acc[m][2 * p], u = acc[m][2 * p + 1];
#pragma unroll
        for (int jj = 0; jj < 4; jj++) {
          float gv = g[jj];
          float hv = (gv / (1.f + __expf(-gv))) * u[jj];
          r_sh[wr * 64 + m * 16 + rowoff + jj][wc * 32 + p * 16 + rb] = f2bf(hv);
        }
      }
    __syncthreads();
#pragma unroll
    for (int sp = 0; sp < 4; sp++) {
      const int row = sp * 32 + (tid >> 3), col = (tid & 7) * 8;
      *(uint4*)&h_s[(size_t)(mt * 128 + row) * DHID + nt * 64 + col] = *(const uint4*)&r_sh[row][col];
    }
  } else {
    const int id = bid0 - 256;                 // round-robin spreads dead blocks
    const int mti = id >> 2, ntile = id & 3;
    int e, s0, c;
    if (!queue_lookup(cnt, mti, e, s0, c)) return;
    int tok[4];
#pragma unroll
    for (int s = 0; s < 4; ++s) {
      int slot = s0 + s * 32 + (tid >> 3);
      if (slot >= c) slot = c - 1;
      tok[s] = ltok[e * CAP + slot];
    }
    const ushort* Bb = wguTr + ((size_t)e * 512 + ntile * 128) * DHID;
    stage_gather128(xb, tok, 0, smem, tid);
    stage128(Bb, DHID, smem + 16384, tid);
    for (int t = 0; t < 16; ++t) {
      const int co = (t & 1) * 8192;
      const int no = ((t + 1) & 1) * 8192;
      if (t < 15) {
        stage_gather128(xb, tok, (t + 1) * 64, smem + no, tid);
        stage128(Bb + (t + 1) * 64, DHID, smem + 16384 + no, tid);
        SCHED_FENCE();
        VMCNT8();
      } else {
        SCHED_FENCE();
        VMCNT0();
      }
      SCHED_FENCE();
      barrier_raw();
      SCHED_FENCE();
      mfma_tile(smem + co, smem + 16384 + co, wr, wc, lane, acc);
      SCHED_FENCE();
      barrier_raw();
    }
#pragma unroll
    for (int m = 0; m < 4; m++)
#pragma unroll
      for (int jj = 0; jj < 4; jj++) {
        const int slot = s0 + wr * 64 + m * 16 + rowoff + jj;
        const float w = (slot < c) ? lw[e * CAP + slot] : 0.f;
#pragma unroll
        for (int p = 0; p < 2; p++) {
          float gv = acc[m][2 * p][jj];
          float hv = (gv / (1.f + __expf(-gv))) * acc[m][2 * p + 1][jj] * w;
          r_sh[wr * 64 + m * 16 + rowoff + jj][wc * 32 + p * 16 + rb] = f2bf(hv);
        }
      }
    __syncthreads();
#pragma unroll
    for (int sp = 0; sp < 4; sp++) {
      const int row = sp * 32 + (tid >> 3), col = (tid & 7) * 8;
      *(uint4*)&h_r[((size_t)e * CAP + s0 + row) * MR + ntile * 64 + col] = *(const uint4*)&r_sh[row][col];
    }
  }
}

// ---------------- k_down: merged down GEMMs (T4 counted-vmcnt dbuf, sched-fenced) ----------------
__global__ __launch_bounds__(256) void k_down(
    const ushort* __restrict__ h_s, const ushort* __restrict__ wdTs,
    const ushort* __restrict__ h_r, const ushort* __restrict__ wdTr,
    const int* __restrict__ cnt, ushort* __restrict__ ds, ushort* __restrict__ dr)
{
  __shared__ ushort smem[4 * 128 * 64];          // 64 KB
  ushort (*r2)[128] = (ushort(*)[128])smem;
  const int tid = threadIdx.x, lane = tid & 63, wave = tid >> 6;
  const int wr = wave >> 1, wc = wave & 1;
  const int rb = lane & 15, rowoff = (lane >> 4) << 2;
  f32x4 acc[4][4] = {};
  const int bid0 = blockIdx.x;

  const ushort* Ab; const ushort* Bb;
  int K, rowbase, colbase; ushort* outp;
  if (bid0 < 128) {
    const int bid = (bid0 & 7) * 16 + (bid0 >> 3);   // bijective swizzle within [0,128)
    const int mt = bid >> 3, nt = bid & 7;
    Ab = h_s + (size_t)mt * 128 * DHID;
    Bb = wdTs + (size_t)nt * 128 * DHID;
    K = DHID; rowbase = mt * 128; colbase = nt * 128;
    outp = ds;
  } else {
    const int id = bid0 - 128;
    const int mti = id >> 3, nt = id & 7;
    int e, s0, c;
    if (!queue_lookup(cnt, mti, e, s0, c)) return;
    Ab = h_r + ((size_t)e * CAP + s0) * MR;
    Bb = wdTr + ((size_t)e * DHID + nt * 128) * MR;
    K = MR; rowbase = e * CAP + s0; colbase = nt * 128;
    outp = dr;
  }
  const int nk = K >> 6;
  stage128(Ab, K, smem, tid);
  stage128(Bb, K, smem + 16384, tid);
  for (int t = 0; t < nk; ++t) {
    const int co = (t & 1) * 8192;
    const int no = ((t + 1) & 1) * 8192;
    if (t + 1 < nk) {
      stage128(Ab + (t + 1) * 64, K, smem + no, tid);
      stage128(Bb + (t + 1) * 64, K, smem + 16384 + no, tid);
      SCHED_FENCE();
      VMCNT8();
    } else {
      SCHED_FENCE();
      VMCNT0();
    }
    SCHED_FENCE();
    barrier_raw();
    SCHED_FENCE();
    mfma_tile(smem + co, smem + 16384 + co, wr, wc, lane, acc);
    SCHED_FENCE();
    barrier_raw();
  }
#pragma unroll
  for (int m = 0; m < 4; m++)
#pragma unroll
    for (int n = 0; n < 4; n++) {
      f32x4 v = acc[m][n];
#pragma unroll
      for (int jj = 0; jj < 4; jj++)
        r2[wr * 64 + m * 16 + rowoff + jj][wc * 64 + n * 16 + rb] = f2bf(v[jj]);
    }
  __syncthreads();
  {
    const int row = tid >> 1, colE = (tid & 1) * 64;
    ushort* op = &outp[(size_t)(rowbase + row) * DHID + colbase + colE];
#pragma unroll
    for (int q = 0; q < 8; q++)
      *(uint4*)(op + q * 8) = *(const uint4*)&r2[row][colE + q * 8];
  }
}

// ---------------- combine: out[t] = ds[t] + dr[es1] + dr[es2]  (f32 out) ----------------
__global__ __launch_bounds__(256) void k_comb(
    const ushort* __restrict__ ds, const ushort* __restrict__ dr,
    const int* __restrict__ tslot, float* __restrict__ out)
{
  const int tid = threadIdx.x;
  const int t = blockIdx.x * 2 + (tid >> 7);
  const int d = (tid & 127) * 8;
  const int es1 = tslot[t * 2], es2 = tslot[t * 2 + 1];
  uint4 a = *(const uint4*)&ds[(size_t)t * DHID + d];
  float r[8];
  const ushort* ap = (const ushort*)&a;
#pragma unroll
  for (int k = 0; k < 8; ++k) r[k] = bf2f(ap[k]);
  if (es1 >= 0) {
    uint4 b = *(const uint4*)&dr[(size_t)es1 * DHID + d];
    const ushort* bp = (const ushort*)&b;
#pragma unroll
    for (int k = 0; k < 8; ++k) r[k] += bf2f(bp[k]);
  }
  if (es2 >= 0) {
    uint4 b = *(const uint4*)&dr[(size_t)es2 * DHID + d];
    const ushort* bp = (const ushort*)&b;
#pragma unroll
    for (int k = 0; k < 8; ++k) r[k] += bf2f(bp[k]);
  }
  float4* op = (float4*)&out[(size_t)t * DHID + d];
  op[0] = make_float4(r[0], r[1], r[2], r[3]);
  op[1] = make_float4(r[4], r[5], r[6], r[7]);
}

extern "C" void kernel_launch(void* const* d_in, const int* in_sizes, int n_in,
                              void* d_out, int out_size, void* d_ws, size_t ws_size,
                              hipStream_t stream) {
  const float* x    = (const float*)d_in[0];
  const float* rw   = (const float*)d_in[1];
  const float* wg_r = (const float*)d_in[2];
  const float* wu_r = (const float*)d_in[3];
  const float* wd_r = (const float*)d_in[4];
  const float* wg_s = (const float*)d_in[5];
  const float* wu_s = (const float*)d_in[6];
  const float* wd_s = (const float*)d_in[7];
  float* out = (float*)d_out;

  char* ws = (char*)d_ws;
  size_t off = 0;
  ushort* xb    = (ushort*)(ws + off); off += (size_t)T_TOK * DHID * 2;        // 4 MB
  ushort* wguTs = (ushort*)(ws + off); off += (size_t)2048 * DHID * 2;         // 4 MB  interleaved g/u rows
  ushort* wdTs  = (ushort*)(ws + off); off += (size_t)DHID * DHID * 2;         // 2 MB
  ushort* wguTr = (ushort*)(ws + off); off += (size_t)NEXP * 512 * DHID * 2;   // 16 MB interleaved per expert
  ushort* wdTr  = (ushort*)(ws + off); off += (size_t)NEXP * DHID * MR * 2;    // 8 MB
  ushort* h_s   = (ushort*)(ws + off); off += (size_t)T_TOK * DHID * 2;        // 4 MB
  ushort* h_r   = (ushort*)(ws + off); off += (size_t)NEXP * CAP * MR * 2;     // 4 MB
  ushort* ds    = (ushort*)(ws + off); off += (size_t)T_TOK * DHID * 2;        // 4 MB
  ushort* dr    = (ushort*)(ws + off); off += (size_t)NEXP * CAP * DHID * 2;   // 16 MB
  int*    cnt   = (int*)(ws + off);    off += 256;
  int*    ltok  = (int*)(ws + off);    off += (size_t)NEXP * CAP * 4;
  float*  lw    = (float*)(ws + off);  off += (size_t)NEXP * CAP * 4;
  int*    topi  = (int*)(ws + off);    off += (size_t)T_TOK * 4;
  float2* topw  = (float2*)(ws + off); off += (size_t)T_TOK * 8;
  int*    tslot = (int*)(ws + off);    off += (size_t)T_TOK * 2 * 4;
  if (off > ws_size) return;

  TP t0 = {wg_r, wguTr,             DHID, MR,   DHID, 1, (long long)512 * DHID};
  TP t1 = {wu_r, wguTr + 16 * DHID, DHID, MR,   DHID, 1, (long long)512 * DHID};
  TP t2 = {wg_s, wguTs,             DHID, MS,   DHID, 1, (long long)1024 * DHID};
  TP t3 = {wu_s, wguTs + 16 * DHID, DHID, MS,   DHID, 1, (long long)1024 * DHID};
  TP t4 = {wd_r, wdTr,              MR,   DHID, MR,   0, (long long)DHID * MR};
  TP t5 = {wd_s, wdTs,              MS,   DHID, DHID, 0, (long long)MS};

  k_prep<<<T_TOK / 8, 256, 0, stream>>>(x, rw, xb, topi, topw);
  k_build_tp<<<NEXP + 2560, 256, 0, stream>>>(topi, topw, cnt, ltok, lw, tslot, t0, t1, t2, t3);
  k_up<<<512 + 1280, 256, 0, stream>>>(xb, wguTs, wguTr, cnt, ltok, lw, h_s, h_r, t4, t5);
  k_down<<<640, 256, 0, stream>>>(h_s, wdTs, h_r, wdTr, cnt, ds, dr);
  k_comb<<<T_TOK / 2, 256, 0, stream>>>(ds, dr, tslot, out);
}